// Round 8
// baseline (516.623 us; speedup 1.0000x reference)
//
#include <hip/hip_runtime.h>
#include <stdint.h>

#define NPTS 2048
#define KDIM 4096
#define NBLK 512
#define INVALID_KEY 0xFFFFFFFFFFFFFFFFull

typedef __bf16 bf16x8 __attribute__((ext_vector_type(8)));
typedef float f32x4 __attribute__((ext_vector_type(4)));

__device__ __forceinline__ unsigned short f2bf(float f) {
    unsigned int u = __float_as_uint(f);
    u = (u + 0x7FFFu + ((u >> 16) & 1u)) >> 16;   // RNE
    return (unsigned short)u;
}

__device__ __forceinline__ void gld_lds16(const unsigned short* g, unsigned short* l) {
    __builtin_amdgcn_global_load_lds(
        (const __attribute__((address_space(1))) unsigned int*)g,
        (__attribute__((address_space(3))) unsigned int*)l, 16, 0, 0);
}

// key = (d2_bits << 22) | (min(i,j) << 11) | max(i,j): unique per undirected
// edge -> tie-free total order -> hooking cycles are only mutual 2-cycles.
__device__ __forceinline__ unsigned long long mk_key(float w, int i, int j) {
    unsigned long long a = (i < j) ? i : j;
    unsigned long long b = (i < j) ? j : i;
    return ((unsigned long long)__float_as_uint(w) << 22) | (a << 11) | b;
}

// software grid barrier: monotonic epoch counter, device scope.
// All blocks execute identical barrier sequences (merge is deterministic).
__device__ __forceinline__ void gbar(int* cnt, int target) {
    __syncthreads();
    if (threadIdx.x == 0) {
        __threadfence();   // release prior global writes
        __hip_atomic_fetch_add(cnt, 1, __ATOMIC_RELEASE, __HIP_MEMORY_SCOPE_AGENT);
        while (__hip_atomic_load(cnt, __ATOMIC_ACQUIRE, __HIP_MEMORY_SCOPE_AGENT) < target)
            __builtin_amdgcn_s_sleep(8);
    }
    __syncthreads();
}

// ---- Kernel 1: fp32->bf16 convert + sqnorm + state init ------------------
__global__ __launch_bounds__(256) void convert_sqnorm_kernel(const float* __restrict__ x,
                                                             unsigned short* __restrict__ xb,
                                                             float* __restrict__ sq,
                                                             unsigned long long* __restrict__ bestE,
                                                             int* __restrict__ cnt) {
    const int row = blockIdx.x;
    const float* xr = x + (size_t)row * KDIM;
    unsigned short* xbr = xb + (size_t)row * KDIM;
    const int t = threadIdx.x;
    float s = 0.f;
    #pragma unroll
    for (int k = 0; k < 4; ++k) {
        int c = t * 4 + k * 1024;
        float4 v = *(const float4*)(xr + c);
        s += v.x * v.x + v.y * v.y + v.z * v.z + v.w * v.w;
        uint2 u;
        u.x = (unsigned)f2bf(v.x) | ((unsigned)f2bf(v.y) << 16);
        u.y = (unsigned)f2bf(v.z) | ((unsigned)f2bf(v.w) << 16);
        *(uint2*)(xbr + c) = u;
    }
    for (int off = 32; off; off >>= 1) s += __shfl_down(s, off);
    __shared__ float p[4];
    if ((t & 63) == 0) p[t >> 6] = s;
    __syncthreads();
    if (t == 0) {
        sq[row] = p[0] + p[1] + p[2] + p[3];
        bestE[row] = INVALID_KEY;
        if (row == 0) cnt[0] = 0;       // barrier epoch counter (poison-proof init)
    }
}

// ---- Kernel 2: GEMM D2, BK=32, swizzled gLDS staging, fused r0 scan ------
// (R6 structure: 0 bank conflicts, 69 us; XCD swizzle reverted — it regressed)
__global__ __launch_bounds__(256, 2) void gemm_d2_glds(const unsigned short* __restrict__ xb,
                                                       const float* __restrict__ sq,
                                                       float* __restrict__ D2,
                                                       unsigned long long* __restrict__ best0) {
    __shared__ __align__(16) unsigned short tile[12 * 512];  // 12 KB: 0-3 A, 4-11 B
    const int I0 = blockIdx.y * 64;
    const int J0 = blockIdx.x * 128;
    const int t = threadIdx.x;
    const int lane = t & 63;
    const int w = t >> 6;
    const int m = lane & 15, q = lane >> 4;

    const int rp = lane >> 2;
    const int sg = (lane & 3) ^ ((lane >> 3) & 3);
    const unsigned short* gsrc[3]; unsigned short* ldst[3];
    #pragma unroll
    for (int ci = 0; ci < 3; ++ci) {
        int c = w * 3 + ci;
        int rowbase = (c < 4) ? (I0 + c * 16) : (J0 + (c - 4) * 16);
        gsrc[ci] = xb + (size_t)(rowbase + rp) * KDIM + sg * 8;
        ldst[ci] = tile + c * 512;          // wave-uniform base; HW adds lane*16B
    }
    const int fro = m * 32 + ((q ^ ((m >> 1) & 3)) * 8);   // swizzled fragment offset

    f32x4 acc[4][2] = {};
    for (int kc = 0; kc < KDIM; kc += 32) {
        #pragma unroll
        for (int ci = 0; ci < 3; ++ci) gld_lds16(gsrc[ci] + kc, ldst[ci]);
        __syncthreads();
        bf16x8 af[4], bg[2];
        #pragma unroll
        for (int rt = 0; rt < 4; ++rt)
            af[rt] = *(const bf16x8*)(tile + rt * 512 + fro);
        #pragma unroll
        for (int ct = 0; ct < 2; ++ct)
            bg[ct] = *(const bf16x8*)(tile + (4 + w * 2 + ct) * 512 + fro);
        #pragma unroll
        for (int rt = 0; rt < 4; ++rt)
            #pragma unroll
            for (int ct = 0; ct < 2; ++ct)
                acc[rt][ct] = __builtin_amdgcn_mfma_f32_16x16x32_bf16(
                    af[rt], bg[ct], acc[rt][ct], 0, 0, 0);
        __syncthreads();
    }

    // Epilogue: store D2 + fused per-row min-key (round-0 scan).
    // C/D: col = lane&15, row = q*4+reg  [m89/m91-verified]
    unsigned long long* s_best = (unsigned long long*)tile;   // reuse post-barrier
    if (t < 64) s_best[t] = INVALID_KEY;
    __syncthreads();
    #pragma unroll
    for (int rt = 0; rt < 4; ++rt) {
        #pragma unroll
        for (int r = 0; r < 4; ++r) {
            int i = I0 + rt * 16 + q * 4 + r;
            unsigned long long kk = INVALID_KEY;
            #pragma unroll
            for (int ct = 0; ct < 2; ++ct) {
                int j = J0 + w * 32 + ct * 16 + m;
                float v = sq[i] + sq[j] - 2.0f * acc[rt][ct][r];
                v = (i == j) ? __builtin_inff() : fmaxf(v, 0.0f);
                D2[(size_t)i * NPTS + j] = v;
                if (i != j) {
                    unsigned long long key = mk_key(v, i, j);
                    kk = (key < kk) ? key : kk;
                }
            }
            #pragma unroll
            for (int mask = 1; mask < 16; mask <<= 1) {   // butterfly over m
                unsigned long long o = __shfl_xor(kk, mask);
                kk = (o < kk) ? o : kk;
            }
            if (m == 0) atomicMin(&s_best[rt * 16 + q * 4 + r], kk);
        }
    }
    __syncthreads();
    if (t < 64) atomicMin(&best0[I0 + t], s_best[t]);
}

// ---- Kernel 3: ALL Boruvka rounds + sort, one dispatch -------------------
// 512 blocks x 256. Merge computed redundantly & deterministically by every
// block (sc persistent in LDS). bestE single-buffered: valid caches persist;
// only invalidated vertices are rewritten, grid-barriered against readers.
__global__ __launch_bounds__(256, 2) void boruvka_fused(const float* __restrict__ D2,
                                                        unsigned long long* __restrict__ bestE,
                                                        float* __restrict__ ew,
                                                        float* __restrict__ out,
                                                        int* __restrict__ cnt) {
    __shared__ __align__(16) char smem[32768];
    int* sc          = (int*)smem;               // 8 KB, persists across rounds
    unsigned* compW  = (unsigned*)(smem + 8192); // 8 KB
    unsigned* compI  = (unsigned*)(smem + 16384);// 8 KB
    int* par         = (int*)(smem + 24576);     // 8 KB, reused as rlist
    float* wl        = (float*)(smem + 8192);    // sort reuse (compW dead)
    __shared__ int s_wsum[4];
    __shared__ int s_nroots, s_ecnt;

    const int t = threadIdx.x;
    const int bid = blockIdx.x;
    const int lane = t & 63, w = t >> 6;
    int ep = 0;

    if (t == 0) s_ecnt = 0;
    #pragma unroll
    for (int e = 0; e < 8; ++e) sc[t * 8 + e] = t * 8 + e;
    __syncthreads();

    for (int r = 0; r < 11; ++r) {
        #pragma unroll
        for (int e = 0; e < 8; ++e) {
            compW[t * 8 + e] = 0xFFFFFFFFu;
            compI[t * 8 + e] = 0xFFFFFFFFu;
        }
        if (t == 0) s_nroots = 0;
        __syncthreads();

        // component reduce (two-phase u32: min weight, then min edge-id)
        unsigned w32[8], id22[8]; int oreg[8], scv[8]; bool val[8], ext[8];
        #pragma unroll
        for (int e = 0; e < 8; ++e) {
            int v = t * 8 + e;
            unsigned long long k = bestE[v];
            w32[e] = (unsigned)(k >> 22);
            id22[e] = (unsigned)(k & 0x3FFFFFu);
            int a = (int)(id22[e] >> 11), b = (int)(id22[e] & 2047);
            oreg[e] = (a == v) ? b : a;
            scv[e] = sc[v];
            val[e] = (k != INVALID_KEY);
            ext[e] = val[e] && (sc[oreg[e]] != scv[e]);
            if (ext[e]) atomicMin(&compW[scv[e]], w32[e]);
        }
        __syncthreads();
        #pragma unroll
        for (int e = 0; e < 8; ++e)
            if (ext[e] && w32[e] == compW[scv[e]]) atomicMin(&compI[scv[e]], id22[e]);
        __syncthreads();

        // hook roots (smaller root survives mutual 2-cycle); block 0 records
        bool isr[8];
        #pragma unroll
        for (int e = 0; e < 8; ++e) {
            int c = t * 8 + e;
            int p = c;
            isr[e] = (sc[c] == c);
            if (isr[e]) {
                unsigned wv = compW[c];
                if (wv != 0xFFFFFFFFu) {
                    unsigned id = compI[c];
                    int a = (int)(id >> 11), b = (int)(id & 2047);
                    int j = (sc[a] == c) ? b : a;
                    int rj = sc[j];
                    bool mutual = (compW[rj] == wv) && (compI[rj] == id);
                    if (!(mutual && c < rj)) {
                        p = rj;
                        if (bid == 0)
                            ew[atomicAdd(&s_ecnt, 1)] = __uint_as_float(wv);
                    }
                }
            }
            par[c] = p;
        }
        // pointer-jump to convergence (races benign: reads are ancestors)
        int any = __syncthreads_or(1);
        do {
            int local = 0;
            #pragma unroll
            for (int e = 0; e < 8; ++e) {
                if (isr[e]) {
                    int c = t * 8 + e;
                    int p = par[c];
                    int np = par[p];
                    if (np != p) { par[c] = np; local = 1; }
                }
            }
            any = __syncthreads_or(local);
        } while (any);

        int newsc[8]; int rc = 0;
        #pragma unroll
        for (int e = 0; e < 8; ++e) {
            int v = t * 8 + e;
            newsc[e] = par[sc[v]];      // own sc slot + stable par
            if (newsc[e] == v) rc++;
        }
        if (rc) atomicAdd(&s_nroots, rc);
        #pragma unroll
        for (int e = 0; e < 8; ++e) sc[t * 8 + e] = newsc[e];
        __syncthreads();
        if (s_nroots == 1) break;       // uniform across blocks (deterministic)

        // rescan list = vertices whose cached edge became internal
        int flags[8], lc = 0;
        #pragma unroll
        for (int e = 0; e < 8; ++e) {
            int v = t * 8 + e;
            flags[e] = (!val[e]) || (sc[oreg[e]] == sc[v]);
            lc += flags[e];
        }
        int scn = lc;
        #pragma unroll
        for (int d = 1; d < 64; d <<= 1) {
            int o = __shfl_up(scn, d);
            if (lane >= d) scn += o;
        }
        if (lane == 63) s_wsum[w] = scn;
        __syncthreads();
        int wbase = 0;
        for (int i = 0; i < w; ++i) wbase += s_wsum[i];
        const int cntl = s_wsum[0] + s_wsum[1] + s_wsum[2] + s_wsum[3];
        int base = wbase + scn - lc;
        int* rlist = par;               // par dead
        #pragma unroll
        for (int e = 0; e < 8; ++e)
            if (flags[e]) rlist[base++] = t * 8 + e;

        gbar(cnt, NBLK * ++ep);         // all blocks done READING bestE

        int widx = bid * 4 + w;
        if (widx < cntl) {
            int v = rlist[widx];
            int mc = sc[v];
            const float* row = D2 + (size_t)v * NPTS;
            unsigned long long best = INVALID_KEY;
            #pragma unroll
            for (int k = 0; k < 8; ++k) {
                int j0 = k * 256 + lane * 4;
                float4 w4 = *(const float4*)(row + j0);
                int4 c4 = *(const int4*)(sc + j0);
                float wa[4] = {w4.x, w4.y, w4.z, w4.w};
                int ca[4] = {c4.x, c4.y, c4.z, c4.w};
                #pragma unroll
                for (int e = 0; e < 4; ++e) {
                    if (ca[e] != mc) {
                        unsigned long long key = mk_key(wa[e], v, j0 + e);
                        best = (key < best) ? key : best;
                    }
                }
            }
            for (int off = 32; off; off >>= 1) {
                unsigned long long o = __shfl_down(best, off);
                best = (o < best) ? o : best;
            }
            if (lane == 0) bestE[v] = best;
        }
        gbar(cnt, NBLK * ++ep);         // rescan writes visible to all
    }

    // block 0: bitonic sort 2048 (2047 edges + inf pad), sqrt, write out
    if (bid == 0) {
        __syncthreads();
        for (int i = t; i < NPTS; i += 256)
            wl[i] = (i < NPTS - 1) ? ew[i] : __builtin_inff();
        __syncthreads();
        for (int k = 2; k <= NPTS; k <<= 1) {
            for (int j = k >> 1; j > 0; j >>= 1) {
                for (int i = t; i < NPTS; i += 256) {
                    int l = i ^ j;
                    if (l > i) {
                        float a = wl[i], b = wl[l];
                        bool up = ((i & k) == 0);
                        if ((a > b) == up) { wl[i] = b; wl[l] = a; }
                    }
                }
                __syncthreads();
            }
        }
        for (int i = t; i < NPTS - 1; i += 256)
            out[i] = sqrtf(fmaxf(wl[i], 0.0f));
    }
}

extern "C" void kernel_launch(void* const* d_in, const int* in_sizes, int n_in,
                              void* d_out, int out_size, void* d_ws, size_t ws_size,
                              hipStream_t stream) {
    const float* x = (const float*)d_in[0];
    float* out = (float*)d_out;
    char* ws = (char*)d_ws;
    unsigned short* xb = (unsigned short*)ws;                          // 16 MB
    float* D2 = (float*)(ws + 16777216);                               // 16 MB
    size_t o = 33554432;
    float* sq = (float*)(ws + o);                  o += 8192;
    unsigned long long* bestE = (unsigned long long*)(ws + o); o += 16384;
    float* ew = (float*)(ws + o);                  o += 8192;
    int* cnt = (int*)(ws + o);

    hipLaunchKernelGGL(convert_sqnorm_kernel, dim3(NPTS), dim3(256), 0, stream,
                       x, xb, sq, bestE, cnt);
    hipLaunchKernelGGL(gemm_d2_glds, dim3(16, 32), dim3(256), 0, stream,
                       xb, sq, D2, bestE);
    hipLaunchKernelGGL(boruvka_fused, dim3(NBLK), dim3(256), 0, stream,
                       D2, bestE, ew, out, cnt);
}

// Round 9
// 287.898 us; speedup vs baseline: 1.7945x; 1.7945x over previous
//
#include <hip/hip_runtime.h>
#include <stdint.h>

#define NPTS 2048
#define KDIM 4096
#define FBLK 64
#define INVALID_KEY 0xFFFFFFFFFFFFFFFFull

typedef __bf16 bf16x8 __attribute__((ext_vector_type(8)));
typedef float f32x4 __attribute__((ext_vector_type(4)));

__device__ __forceinline__ unsigned short f2bf(float f) {
    unsigned int u = __float_as_uint(f);
    u = (u + 0x7FFFu + ((u >> 16) & 1u)) >> 16;   // RNE
    return (unsigned short)u;
}

__device__ __forceinline__ void gld_lds16(const unsigned short* g, unsigned short* l) {
    __builtin_amdgcn_global_load_lds(
        (const __attribute__((address_space(1))) unsigned int*)g,
        (__attribute__((address_space(3))) unsigned int*)l, 16, 0, 0);
}

// key = (d2_bits << 22) | (min(i,j) << 11) | max(i,j): unique per undirected
// edge -> tie-free total order -> hooking cycles are only mutual 2-cycles.
__device__ __forceinline__ unsigned long long mk_key(float w, int i, int j) {
    unsigned long long a = (i < j) ? i : j;
    unsigned long long b = (i < j) ? j : i;
    return ((unsigned long long)__float_as_uint(w) << 22) | (a << 11) | b;
}

// epoch spin barrier — ONLY safe because grid (64 blocks) << residency limit.
__device__ __forceinline__ void gbar(int* bar, int target) {
    __syncthreads();
    if (threadIdx.x == 0) {
        __threadfence();
        __hip_atomic_fetch_add(bar, 1, __ATOMIC_RELEASE, __HIP_MEMORY_SCOPE_AGENT);
        while (__hip_atomic_load(bar, __ATOMIC_ACQUIRE, __HIP_MEMORY_SCOPE_AGENT) < target)
            __builtin_amdgcn_s_sleep(8);
        __threadfence();
    }
    __syncthreads();
}

// ---- Kernel 1: fp32->bf16 convert + sqnorm + state init ------------------
__global__ __launch_bounds__(256) void convert_sqnorm_kernel(const float* __restrict__ x,
                                                             unsigned short* __restrict__ xb,
                                                             float* __restrict__ sq,
                                                             unsigned long long* __restrict__ best0,
                                                             int* __restrict__ ctl,
                                                             int* __restrict__ bar) {
    const int row = blockIdx.x;
    const float* xr = x + (size_t)row * KDIM;
    unsigned short* xbr = xb + (size_t)row * KDIM;
    const int t = threadIdx.x;
    float s = 0.f;
    #pragma unroll
    for (int k = 0; k < 4; ++k) {
        int c = t * 4 + k * 1024;
        float4 v = *(const float4*)(xr + c);
        s += v.x * v.x + v.y * v.y + v.z * v.z + v.w * v.w;
        uint2 u;
        u.x = (unsigned)f2bf(v.x) | ((unsigned)f2bf(v.y) << 16);
        u.y = (unsigned)f2bf(v.z) | ((unsigned)f2bf(v.w) << 16);
        *(uint2*)(xbr + c) = u;
    }
    for (int off = 32; off; off >>= 1) s += __shfl_down(s, off);
    __shared__ float p[4];
    if ((t & 63) == 0) p[t >> 6] = s;
    __syncthreads();
    if (t == 0) {
        sq[row] = p[0] + p[1] + p[2] + p[3];
        best0[row] = INVALID_KEY;
        if (row == 0) { ctl[0] = 0; bar[0] = 0; }
    }
}

// ---- Kernel 2: GEMM D2, BK=32, swizzled gLDS staging, fused r0 scan ------
// (R6 exact: 0 bank conflicts, ~69 us)
__global__ __launch_bounds__(256, 2) void gemm_d2_glds(const unsigned short* __restrict__ xb,
                                                       const float* __restrict__ sq,
                                                       float* __restrict__ D2,
                                                       unsigned long long* __restrict__ best0) {
    __shared__ __align__(16) unsigned short tile[12 * 512];  // 12 KB: 0-3 A, 4-11 B
    const int I0 = blockIdx.y * 64;
    const int J0 = blockIdx.x * 128;
    const int t = threadIdx.x;
    const int lane = t & 63;
    const int w = t >> 6;
    const int m = lane & 15, q = lane >> 4;

    const int rp = lane >> 2;
    const int sg = (lane & 3) ^ ((lane >> 3) & 3);
    const unsigned short* gsrc[3]; unsigned short* ldst[3];
    #pragma unroll
    for (int ci = 0; ci < 3; ++ci) {
        int c = w * 3 + ci;
        int rowbase = (c < 4) ? (I0 + c * 16) : (J0 + (c - 4) * 16);
        gsrc[ci] = xb + (size_t)(rowbase + rp) * KDIM + sg * 8;
        ldst[ci] = tile + c * 512;          // wave-uniform base; HW adds lane*16B
    }
    const int fro = m * 32 + ((q ^ ((m >> 1) & 3)) * 8);   // swizzled fragment offset

    f32x4 acc[4][2] = {};
    for (int kc = 0; kc < KDIM; kc += 32) {
        #pragma unroll
        for (int ci = 0; ci < 3; ++ci) gld_lds16(gsrc[ci] + kc, ldst[ci]);
        __syncthreads();
        bf16x8 af[4], bg[2];
        #pragma unroll
        for (int rt = 0; rt < 4; ++rt)
            af[rt] = *(const bf16x8*)(tile + rt * 512 + fro);
        #pragma unroll
        for (int ct = 0; ct < 2; ++ct)
            bg[ct] = *(const bf16x8*)(tile + (4 + w * 2 + ct) * 512 + fro);
        #pragma unroll
        for (int rt = 0; rt < 4; ++rt)
            #pragma unroll
            for (int ct = 0; ct < 2; ++ct)
                acc[rt][ct] = __builtin_amdgcn_mfma_f32_16x16x32_bf16(
                    af[rt], bg[ct], acc[rt][ct], 0, 0, 0);
        __syncthreads();
    }

    // Epilogue: store D2 + fused per-row min-key (round-0 scan).
    // C/D: col = lane&15, row = q*4+reg  [m89/m91-verified]
    unsigned long long* s_best = (unsigned long long*)tile;   // reuse post-barrier
    if (t < 64) s_best[t] = INVALID_KEY;
    __syncthreads();
    #pragma unroll
    for (int rt = 0; rt < 4; ++rt) {
        #pragma unroll
        for (int r = 0; r < 4; ++r) {
            int i = I0 + rt * 16 + q * 4 + r;
            unsigned long long kk = INVALID_KEY;
            #pragma unroll
            for (int ct = 0; ct < 2; ++ct) {
                int j = J0 + w * 32 + ct * 16 + m;
                float v = sq[i] + sq[j] - 2.0f * acc[rt][ct][r];
                v = (i == j) ? __builtin_inff() : fmaxf(v, 0.0f);
                D2[(size_t)i * NPTS + j] = v;
                if (i != j) {
                    unsigned long long key = mk_key(v, i, j);
                    kk = (key < kk) ? key : kk;
                }
            }
            #pragma unroll
            for (int mask = 1; mask < 16; mask <<= 1) {
                unsigned long long o = __shfl_xor(kk, mask);
                kk = (o < kk) ? o : kk;
            }
            if (m == 0) atomicMin(&s_best[rt * 16 + q * 4 + r], kk);
        }
    }
    __syncthreads();
    if (t < 64) atomicMin(&best0[I0 + t], s_best[t]);
}

// ---- Kernel 3: round 1 (identity comps -> atomic-free merge) -------------
__global__ __launch_bounds__(256) void boruvka_round1(const float* __restrict__ D2,
                                                      const unsigned long long* __restrict__ bestP,
                                                      unsigned long long* __restrict__ bestN,
                                                      int* __restrict__ compN,
                                                      float* __restrict__ ew,
                                                      int* __restrict__ ctl) {
    __shared__ unsigned compW[NPTS];   // 8 KB: w32 of bestP[v]
    __shared__ unsigned compI[NPTS];   // 8 KB: id22 of bestP[v]
    __shared__ int sc[NPTS];           // 8 KB
    __shared__ int par[NPTS];          // 8 KB, reused as rlist
    __shared__ int s_wsum[4];
    __shared__ int s_ecnt;
    const int t = threadIdx.x;
    const int bid = blockIdx.x;
    const int lane = t & 63, w = t >> 6;

    if (t == 0) s_ecnt = 0;
    unsigned long long kreg[8]; int oreg[8];
    #pragma unroll
    for (int e = 0; e < 8; ++e) {
        int v = t * 8 + e;
        unsigned long long k = bestP[v];
        kreg[e] = k;
        unsigned id = (unsigned)(k & 0x3FFFFFu);
        compW[v] = (unsigned)(k >> 22);
        compI[v] = id;
        int a = (int)(id >> 11), b = (int)(id & 2047);
        oreg[e] = (a == v) ? b : a;
    }
    __syncthreads();

    // hook: every vertex is a root; mutual pair <=> same edge id both sides
    #pragma unroll
    for (int e = 0; e < 8; ++e) {
        int c = t * 8 + e;
        unsigned id = compI[c];
        int j = oreg[e];
        bool mutual = (compI[j] == id);
        int p;
        if (mutual && c < j) p = c;
        else {
            p = j;
            if (bid == 0) ew[atomicAdd(&s_ecnt, 1)] = __uint_as_float(compW[c]);
        }
        par[c] = p;
    }
    int any = __syncthreads_or(1);
    do {
        int local = 0;
        #pragma unroll
        for (int e = 0; e < 8; ++e) {
            int c = t * 8 + e;
            int p = par[c];
            int np = par[p];
            if (np != p) { par[c] = np; local = 1; }
        }
        any = __syncthreads_or(local);
    } while (any);

    int newsc[8];
    #pragma unroll
    for (int e = 0; e < 8; ++e) newsc[e] = par[t * 8 + e];
    __syncthreads();
    #pragma unroll
    for (int e = 0; e < 8; ++e) sc[t * 8 + e] = newsc[e];
    __syncthreads();

    if (bid == 0) {
        #pragma unroll
        for (int e = 0; e < 8; ++e) compN[t * 8 + e] = newsc[e];
        if (t == 0) ctl[0] = s_ecnt;
    }

    // rescan list = vertices whose cached edge became internal
    int flags[8], lc = 0;
    #pragma unroll
    for (int e = 0; e < 8; ++e) {
        flags[e] = (sc[oreg[e]] == newsc[e]) ? 1 : 0;
        lc += flags[e];
    }
    int scn = lc;
    #pragma unroll
    for (int d = 1; d < 64; d <<= 1) {
        int o = __shfl_up(scn, d);
        if (lane >= d) scn += o;
    }
    if (lane == 63) s_wsum[w] = scn;
    __syncthreads();
    int wbase = 0;
    for (int i = 0; i < w; ++i) wbase += s_wsum[i];
    const int ncand = s_wsum[0] + s_wsum[1] + s_wsum[2] + s_wsum[3];
    int base = wbase + scn - lc;
    int* rlist = par;    // par dead
    #pragma unroll
    for (int e = 0; e < 8; ++e)
        if (flags[e]) rlist[base++] = t * 8 + e;
    __syncthreads();

    // carry-over valid caches: block bid owns vertices [bid*4, bid*4+4)
    if (t < 4) {
        int v = bid * 4 + t;
        unsigned long long k = bestP[v];
        unsigned id = (unsigned)(k & 0x3FFFFFu);
        int a = (int)(id >> 11), b = (int)(id & 2047);
        int o = (a == v) ? b : a;
        if (sc[o] != sc[v]) bestN[v] = k;
    }
    // rescan: wave w handles rlist[bid*4 + w]
    int widx = bid * 4 + w;
    if (widx < ncand) {
        int v = rlist[widx];
        int mc = sc[v];
        const float* row = D2 + (size_t)v * NPTS;
        unsigned long long best = INVALID_KEY;
        #pragma unroll
        for (int k = 0; k < 8; ++k) {
            int j0 = k * 256 + lane * 4;
            float4 w4 = *(const float4*)(row + j0);
            int4 c4 = *(const int4*)(sc + j0);
            float wa[4] = {w4.x, w4.y, w4.z, w4.w};
            int ca[4] = {c4.x, c4.y, c4.z, c4.w};
            #pragma unroll
            for (int e = 0; e < 4; ++e) {
                if (ca[e] != mc) {
                    unsigned long long key = mk_key(wa[e], v, j0 + e);
                    best = (key < best) ? key : best;
                }
            }
        }
        for (int off = 32; off; off >>= 1) {
            unsigned long long o = __shfl_down(best, off);
            best = (o < best) ? o : best;
        }
        if (lane == 0) bestN[v] = best;
    }
}

// ---- Kernel 4: rounds 2.. + sort, 64 co-resident blocks ------------------
__global__ __launch_bounds__(256) void boruvka_fused(const float* __restrict__ D2,
                                                     unsigned long long* __restrict__ bestE,
                                                     const int* __restrict__ compIn,
                                                     float* __restrict__ ew,
                                                     float* __restrict__ out,
                                                     const int* __restrict__ ctl,
                                                     int* __restrict__ bar) {
    __shared__ int sc[NPTS];            // 8 KB, persists across rounds
    __shared__ unsigned compW[NPTS];    // 8 KB (reused as sort buffer)
    __shared__ unsigned compI[NPTS];    // 8 KB
    __shared__ int par[NPTS];           // 8 KB, reused as rlist
    __shared__ int s_wsum[4];
    __shared__ int s_nroots, s_ecnt;
    const int t = threadIdx.x;
    const int bid = blockIdx.x;
    const int lane = t & 63, w = t >> 6;
    int ep = 0;

    if (t == 0) s_ecnt = ctl[0];
    #pragma unroll
    for (int e = 0; e < 8; ++e) sc[t * 8 + e] = compIn[t * 8 + e];
    __syncthreads();

    for (int r = 0; r < 10; ++r) {
        #pragma unroll
        for (int e = 0; e < 8; ++e) {
            compW[t * 8 + e] = 0xFFFFFFFFu;
            compI[t * 8 + e] = 0xFFFFFFFFu;
        }
        if (t == 0) s_nroots = 0;
        __syncthreads();

        unsigned long long kk[8]; int oreg[8], scv[8]; bool val[8], contrib[8];
        #pragma unroll
        for (int e = 0; e < 8; ++e) {
            int v = t * 8 + e;
            unsigned long long k = bestE[v];
            kk[e] = k;
            unsigned id = (unsigned)(k & 0x3FFFFFu);
            int a = (int)(id >> 11), b = (int)(id & 2047);
            oreg[e] = (a == v) ? b : a;
            scv[e] = sc[v];
            val[e] = (k != INVALID_KEY);
            contrib[e] = val[e] && (sc[oreg[e]] != scv[e]);
        }
        // thread-local dedup (late rounds: few comps -> cuts atomic storm ~8x)
        #pragma unroll
        for (int e = 1; e < 8; ++e) {
            if (contrib[e]) {
                #pragma unroll
                for (int f = 0; f < e; ++f) {
                    if (contrib[f] && scv[f] == scv[e]) {
                        if (kk[e] < kk[f]) kk[f] = kk[e];
                        contrib[e] = false;
                        break;
                    }
                }
            }
        }
        #pragma unroll
        for (int e = 0; e < 8; ++e)
            if (contrib[e]) atomicMin(&compW[scv[e]], (unsigned)(kk[e] >> 22));
        __syncthreads();
        #pragma unroll
        for (int e = 0; e < 8; ++e)
            if (contrib[e] && (unsigned)(kk[e] >> 22) == compW[scv[e]])
                atomicMin(&compI[scv[e]], (unsigned)(kk[e] & 0x3FFFFFu));
        __syncthreads();

        bool isr[8];
        #pragma unroll
        for (int e = 0; e < 8; ++e) {
            int c = t * 8 + e;
            int p = c;
            isr[e] = (sc[c] == c);
            if (isr[e]) {
                unsigned wv = compW[c];
                if (wv != 0xFFFFFFFFu) {
                    unsigned id = compI[c];
                    int a = (int)(id >> 11), b = (int)(id & 2047);
                    int j = (sc[a] == c) ? b : a;
                    int rj = sc[j];
                    bool mutual = (compW[rj] == wv) && (compI[rj] == id);
                    if (!(mutual && c < rj)) {
                        p = rj;
                        if (bid == 0)
                            ew[atomicAdd(&s_ecnt, 1)] = __uint_as_float(wv);
                    }
                }
            }
            par[c] = p;
        }
        int any = __syncthreads_or(1);
        do {
            int local = 0;
            #pragma unroll
            for (int e = 0; e < 8; ++e) {
                if (isr[e]) {
                    int c = t * 8 + e;
                    int p = par[c];
                    int np = par[p];
                    if (np != p) { par[c] = np; local = 1; }
                }
            }
            any = __syncthreads_or(local);
        } while (any);

        int newsc[8]; int rc = 0;
        #pragma unroll
        for (int e = 0; e < 8; ++e) {
            int v = t * 8 + e;
            newsc[e] = par[sc[v]];
            if (newsc[e] == v) rc++;
        }
        if (rc) atomicAdd(&s_nroots, rc);
        __syncthreads();
        #pragma unroll
        for (int e = 0; e < 8; ++e) sc[t * 8 + e] = newsc[e];
        __syncthreads();
        if (s_nroots == 1) break;   // uniform across blocks (deterministic merge)

        int flags[8], lc = 0;
        #pragma unroll
        for (int e = 0; e < 8; ++e) {
            int v = t * 8 + e;
            flags[e] = (!val[e]) || (sc[oreg[e]] == sc[v]);
            lc += flags[e];
        }
        int scn = lc;
        #pragma unroll
        for (int d = 1; d < 64; d <<= 1) {
            int o = __shfl_up(scn, d);
            if (lane >= d) scn += o;
        }
        if (lane == 63) s_wsum[w] = scn;
        __syncthreads();
        int wbase = 0;
        for (int i = 0; i < w; ++i) wbase += s_wsum[i];
        const int ncand = s_wsum[0] + s_wsum[1] + s_wsum[2] + s_wsum[3];
        int base = wbase + scn - lc;
        int* rlist = par;   // par dead
        #pragma unroll
        for (int e = 0; e < 8; ++e)
            if (flags[e]) rlist[base++] = t * 8 + e;

        gbar(bar, FBLK * ++ep);     // all blocks done reading bestE; rlist ready

        for (int widx = bid * 4 + w; widx < ncand; widx += FBLK * 4) {
            int v = rlist[widx];
            int mc = sc[v];
            const float* row = D2 + (size_t)v * NPTS;
            unsigned long long best = INVALID_KEY;
            #pragma unroll
            for (int k = 0; k < 8; ++k) {
                int j0 = k * 256 + lane * 4;
                float4 w4 = *(const float4*)(row + j0);
                int4 c4 = *(const int4*)(sc + j0);
                float wa[4] = {w4.x, w4.y, w4.z, w4.w};
                int ca[4] = {c4.x, c4.y, c4.z, c4.w};
                #pragma unroll
                for (int e = 0; e < 4; ++e) {
                    if (ca[e] != mc) {
                        unsigned long long key = mk_key(wa[e], v, j0 + e);
                        best = (key < best) ? key : best;
                    }
                }
            }
            for (int off = 32; off; off >>= 1) {
                unsigned long long o = __shfl_down(best, off);
                best = (o < best) ? o : best;
            }
            if (lane == 0) bestE[v] = best;
        }
        gbar(bar, FBLK * ++ep);     // rescan writes visible to all
    }

    // block 0: bitonic sort 2048 (2047 edges + inf pad), sqrt, write out
    if (bid == 0) {
        float* wl = (float*)compW;
        __syncthreads();
        for (int i = t; i < NPTS; i += 256)
            wl[i] = (i < NPTS - 1) ? ew[i] : __builtin_inff();
        __syncthreads();
        for (int k = 2; k <= NPTS; k <<= 1) {
            for (int j = k >> 1; j > 0; j >>= 1) {
                for (int i = t; i < NPTS; i += 256) {
                    int l = i ^ j;
                    if (l > i) {
                        float a = wl[i], b = wl[l];
                        bool up = ((i & k) == 0);
                        if ((a > b) == up) { wl[i] = b; wl[l] = a; }
                    }
                }
                __syncthreads();
            }
        }
        for (int i = t; i < NPTS - 1; i += 256)
            out[i] = sqrtf(fmaxf(wl[i], 0.0f));
    }
}

extern "C" void kernel_launch(void* const* d_in, const int* in_sizes, int n_in,
                              void* d_out, int out_size, void* d_ws, size_t ws_size,
                              hipStream_t stream) {
    const float* x = (const float*)d_in[0];
    float* out = (float*)d_out;
    char* ws = (char*)d_ws;
    unsigned short* xb = (unsigned short*)ws;                          // 16 MB
    float* D2 = (float*)(ws + 16777216);                               // 16 MB
    size_t o = 33554432;
    float* sq = (float*)(ws + o);                  o += 8192;
    unsigned long long* best0 = (unsigned long long*)(ws + o); o += 16384;
    unsigned long long* best1 = (unsigned long long*)(ws + o); o += 16384;
    int* comp = (int*)(ws + o);                    o += 8192;
    float* ew = (float*)(ws + o);                  o += 8192;
    int* ctl = (int*)(ws + o);                     o += 4096;
    int* bar = (int*)(ws + o);

    hipLaunchKernelGGL(convert_sqnorm_kernel, dim3(NPTS), dim3(256), 0, stream,
                       x, xb, sq, best0, ctl, bar);
    hipLaunchKernelGGL(gemm_d2_glds, dim3(16, 32), dim3(256), 0, stream,
                       xb, sq, D2, best0);
    hipLaunchKernelGGL(boruvka_round1, dim3(512), dim3(256), 0, stream,
                       D2, best0, best1, comp, ew, ctl);
    hipLaunchKernelGGL(boruvka_fused, dim3(FBLK), dim3(256), 0, stream,
                       D2, best1, comp, ew, out, ctl, bar);
}

// Round 10
// 244.870 us; speedup vs baseline: 2.1098x; 1.1757x over previous
//
#include <hip/hip_runtime.h>
#include <stdint.h>

#define NPTS 2048
#define KDIM 4096
#define CMAX 512
#define INVALID_KEY 0xFFFFFFFFFFFFFFFFull

typedef __bf16 bf16x8 __attribute__((ext_vector_type(8)));
typedef float f32x4 __attribute__((ext_vector_type(4)));
typedef unsigned long long u64;

__device__ __forceinline__ unsigned short f2bf(float f) {
    unsigned int u = __float_as_uint(f);
    u = (u + 0x7FFFu + ((u >> 16) & 1u)) >> 16;   // RNE
    return (unsigned short)u;
}

__device__ __forceinline__ void gld_lds16(const unsigned short* g, unsigned short* l) {
    __builtin_amdgcn_global_load_lds(
        (const __attribute__((address_space(1))) unsigned int*)g,
        (__attribute__((address_space(3))) unsigned int*)l, 16, 0, 0);
}

// key = (d2_bits << 22) | (min(i,j) << 11) | max(i,j): unique per undirected
// edge -> tie-free total order; uniqueness survives contraction, so the
// condensed graph inherits a tie-free order too.
__device__ __forceinline__ u64 mk_key(float w, int i, int j) {
    u64 a = (i < j) ? i : j;
    u64 b = (i < j) ? j : i;
    return ((u64)__float_as_uint(w) << 22) | (a << 11) | b;
}

// ---- Kernel 1: fp32->bf16 convert + sqnorm + state init ------------------
__global__ __launch_bounds__(256) void convert_sqnorm_kernel(const float* __restrict__ x,
                                                             unsigned short* __restrict__ xb,
                                                             float* __restrict__ sq,
                                                             u64* __restrict__ best0,
                                                             int* __restrict__ ctl) {
    const int row = blockIdx.x;
    const float* xr = x + (size_t)row * KDIM;
    unsigned short* xbr = xb + (size_t)row * KDIM;
    const int t = threadIdx.x;
    float s = 0.f;
    #pragma unroll
    for (int k = 0; k < 4; ++k) {
        int c = t * 4 + k * 1024;
        float4 v = *(const float4*)(xr + c);
        s += v.x * v.x + v.y * v.y + v.z * v.z + v.w * v.w;
        uint2 u;
        u.x = (unsigned)f2bf(v.x) | ((unsigned)f2bf(v.y) << 16);
        u.y = (unsigned)f2bf(v.z) | ((unsigned)f2bf(v.w) << 16);
        *(uint2*)(xbr + c) = u;
    }
    for (int off = 32; off; off >>= 1) s += __shfl_down(s, off);
    __shared__ float p[4];
    if ((t & 63) == 0) p[t >> 6] = s;
    __syncthreads();
    if (t == 0) {
        sq[row] = p[0] + p[1] + p[2] + p[3];
        best0[row] = INVALID_KEY;
        if (row == 0) { ctl[0] = 0; ctl[1] = 0; }
    }
}

// ---- Kernel 2: GEMM D2, BK=32, swizzled gLDS staging, fused r0 scan ------
// (R6 exact: 0 bank conflicts, ~69 us)
__global__ __launch_bounds__(256, 2) void gemm_d2_glds(const unsigned short* __restrict__ xb,
                                                       const float* __restrict__ sq,
                                                       float* __restrict__ D2,
                                                       u64* __restrict__ best0) {
    __shared__ __align__(16) unsigned short tile[12 * 512];  // 12 KB: 0-3 A, 4-11 B
    const int I0 = blockIdx.y * 64;
    const int J0 = blockIdx.x * 128;
    const int t = threadIdx.x;
    const int lane = t & 63;
    const int w = t >> 6;
    const int m = lane & 15, q = lane >> 4;

    const int rp = lane >> 2;
    const int sg = (lane & 3) ^ ((lane >> 3) & 3);
    const unsigned short* gsrc[3]; unsigned short* ldst[3];
    #pragma unroll
    for (int ci = 0; ci < 3; ++ci) {
        int c = w * 3 + ci;
        int rowbase = (c < 4) ? (I0 + c * 16) : (J0 + (c - 4) * 16);
        gsrc[ci] = xb + (size_t)(rowbase + rp) * KDIM + sg * 8;
        ldst[ci] = tile + c * 512;          // wave-uniform base; HW adds lane*16B
    }
    const int fro = m * 32 + ((q ^ ((m >> 1) & 3)) * 8);

    f32x4 acc[4][2] = {};
    for (int kc = 0; kc < KDIM; kc += 32) {
        #pragma unroll
        for (int ci = 0; ci < 3; ++ci) gld_lds16(gsrc[ci] + kc, ldst[ci]);
        __syncthreads();
        bf16x8 af[4], bg[2];
        #pragma unroll
        for (int rt = 0; rt < 4; ++rt)
            af[rt] = *(const bf16x8*)(tile + rt * 512 + fro);
        #pragma unroll
        for (int ct = 0; ct < 2; ++ct)
            bg[ct] = *(const bf16x8*)(tile + (4 + w * 2 + ct) * 512 + fro);
        #pragma unroll
        for (int rt = 0; rt < 4; ++rt)
            #pragma unroll
            for (int ct = 0; ct < 2; ++ct)
                acc[rt][ct] = __builtin_amdgcn_mfma_f32_16x16x32_bf16(
                    af[rt], bg[ct], acc[rt][ct], 0, 0, 0);
        __syncthreads();
    }

    // Epilogue: store D2 + fused per-row min-key (round-0 scan).
    u64* s_best = (u64*)tile;
    if (t < 64) s_best[t] = INVALID_KEY;
    __syncthreads();
    #pragma unroll
    for (int rt = 0; rt < 4; ++rt) {
        #pragma unroll
        for (int r = 0; r < 4; ++r) {
            int i = I0 + rt * 16 + q * 4 + r;
            u64 kk = INVALID_KEY;
            #pragma unroll
            for (int ct = 0; ct < 2; ++ct) {
                int j = J0 + w * 32 + ct * 16 + m;
                float v = sq[i] + sq[j] - 2.0f * acc[rt][ct][r];
                v = (i == j) ? __builtin_inff() : fmaxf(v, 0.0f);
                D2[(size_t)i * NPTS + j] = v;
                if (i != j) {
                    u64 key = mk_key(v, i, j);
                    kk = (key < kk) ? key : kk;
                }
            }
            #pragma unroll
            for (int mask = 1; mask < 16; mask <<= 1) {
                u64 o = __shfl_xor(kk, mask);
                kk = (o < kk) ? o : kk;
            }
            if (m == 0) atomicMin(&s_best[rt * 16 + q * 4 + r], kk);
        }
    }
    __syncthreads();
    if (t < 64) atomicMin(&best0[I0 + t], s_best[t]);
}

// ---- Kernel 3: round 1 (identity comps, atomic-free merge) + M/cand init -
__global__ __launch_bounds__(256) void boruvka_round1(const float* __restrict__ D2,
                                                      const u64* __restrict__ bestP,
                                                      u64* __restrict__ bestN,
                                                      int* __restrict__ compN,
                                                      float* __restrict__ ew,
                                                      int* __restrict__ ctl,
                                                      u64* __restrict__ M,
                                                      u64* __restrict__ cand) {
    __shared__ unsigned compW[NPTS];
    __shared__ unsigned compI[NPTS];
    __shared__ int sc[NPTS];
    __shared__ int par[NPTS];
    __shared__ int s_wsum[4];
    __shared__ int s_ecnt;
    const int t = threadIdx.x;
    const int bid = blockIdx.x;
    const int lane = t & 63, w = t >> 6;

    // init condensed-graph buffers (grid == 512 == CMAX)
    {
        u64* Mb = M + (size_t)bid * CMAX;
        Mb[t] = INVALID_KEY; Mb[t + 256] = INVALID_KEY;
        if (t == 0) cand[bid] = INVALID_KEY;
    }

    if (t == 0) s_ecnt = 0;
    int oreg[8];
    #pragma unroll
    for (int e = 0; e < 8; ++e) {
        int v = t * 8 + e;
        u64 k = bestP[v];
        unsigned id = (unsigned)(k & 0x3FFFFFu);
        compW[v] = (unsigned)(k >> 22);
        compI[v] = id;
        int a = (int)(id >> 11), b = (int)(id & 2047);
        oreg[e] = (a == v) ? b : a;
    }
    __syncthreads();

    #pragma unroll
    for (int e = 0; e < 8; ++e) {
        int c = t * 8 + e;
        unsigned id = compI[c];
        int j = oreg[e];
        bool mutual = (compI[j] == id);
        int p;
        if (mutual && c < j) p = c;
        else {
            p = j;
            if (bid == 0) ew[atomicAdd(&s_ecnt, 1)] = __uint_as_float(compW[c]);
        }
        par[c] = p;
    }
    int any = __syncthreads_or(1);
    do {
        int local = 0;
        #pragma unroll
        for (int e = 0; e < 8; ++e) {
            int c = t * 8 + e;
            int p = par[c];
            int np = par[p];
            if (np != p) { par[c] = np; local = 1; }
        }
        any = __syncthreads_or(local);
    } while (any);

    int newsc[8];
    #pragma unroll
    for (int e = 0; e < 8; ++e) newsc[e] = par[t * 8 + e];
    __syncthreads();
    #pragma unroll
    for (int e = 0; e < 8; ++e) sc[t * 8 + e] = newsc[e];
    __syncthreads();

    if (bid == 0) {
        #pragma unroll
        for (int e = 0; e < 8; ++e) compN[t * 8 + e] = newsc[e];
        if (t == 0) ctl[0] = s_ecnt;
    }

    // rescan list = vertices whose cached edge became internal
    int flags[8], lc = 0;
    #pragma unroll
    for (int e = 0; e < 8; ++e) {
        flags[e] = (sc[oreg[e]] == newsc[e]) ? 1 : 0;
        lc += flags[e];
    }
    int scn = lc;
    #pragma unroll
    for (int d = 1; d < 64; d <<= 1) {
        int o = __shfl_up(scn, d);
        if (lane >= d) scn += o;
    }
    if (lane == 63) s_wsum[w] = scn;
    __syncthreads();
    int wbase = 0;
    for (int i = 0; i < w; ++i) wbase += s_wsum[i];
    const int ncand = s_wsum[0] + s_wsum[1] + s_wsum[2] + s_wsum[3];
    int base = wbase + scn - lc;
    int* rlist = par;
    #pragma unroll
    for (int e = 0; e < 8; ++e)
        if (flags[e]) rlist[base++] = t * 8 + e;
    __syncthreads();

    if (t < 4) {
        int v = bid * 4 + t;
        u64 k = bestP[v];
        unsigned id = (unsigned)(k & 0x3FFFFFu);
        int a = (int)(id >> 11), b = (int)(id & 2047);
        int o = (a == v) ? b : a;
        if (sc[o] != sc[v]) bestN[v] = k;
    }
    int widx = bid * 4 + w;
    if (widx < ncand) {
        int v = rlist[widx];
        int mc = sc[v];
        const float* row = D2 + (size_t)v * NPTS;
        u64 best = INVALID_KEY;
        #pragma unroll
        for (int k = 0; k < 8; ++k) {
            int j0 = k * 256 + lane * 4;
            float4 w4 = *(const float4*)(row + j0);
            int4 c4 = *(const int4*)(sc + j0);
            float wa[4] = {w4.x, w4.y, w4.z, w4.w};
            int ca[4] = {c4.x, c4.y, c4.z, c4.w};
            #pragma unroll
            for (int e = 0; e < 4; ++e) {
                if (ca[e] != mc) {
                    u64 key = mk_key(wa[e], v, j0 + e);
                    best = (key < best) ? key : best;
                }
            }
        }
        for (int off = 32; off; off >>= 1) {
            u64 o = __shfl_down(best, off);
            best = (o < best) ? o : best;
        }
        if (lane == 0) bestN[v] = best;
    }
}

// ---- Kernel 4: round-2 merge + compact relabel + condense to M[512][512] -
__global__ __launch_bounds__(256) void boruvka_r2_condense(const float* __restrict__ D2,
                                                           const u64* __restrict__ bestE,
                                                           const int* __restrict__ compIn,
                                                           float* __restrict__ ew,
                                                           int* __restrict__ ctl,
                                                           int* __restrict__ cscg,
                                                           u64* __restrict__ M,
                                                           u64* __restrict__ cand) {
    __shared__ __align__(16) char smem[32768];
    int* sc         = (int*)smem;               // 8 KB (comp, later csc)
    unsigned* compW = (unsigned*)(smem + 8192); // 8 KB (later: map / Mrow)
    unsigned* compI = (unsigned*)(smem + 16384);// 8 KB (later: Mrow)
    int* par        = (int*)(smem + 24576);     // 8 KB
    u64* Mrow       = (u64*)(smem + 8192);      // 16 KB overlay (4 x 512 u64)
    __shared__ int s_wsum[4];
    __shared__ int s_ecnt;
    const int t = threadIdx.x;
    const int bid = blockIdx.x;
    const int lane = t & 63, w = t >> 6;

    if (t == 0) s_ecnt = ctl[0];
    #pragma unroll
    for (int e = 0; e < 8; ++e) {
        int v = t * 8 + e;
        sc[v] = compIn[v];
        compW[v] = 0xFFFFFFFFu;
        compI[v] = 0xFFFFFFFFu;
    }
    __syncthreads();

    // component reduce (two-phase u32)
    u64 kk[8]; int oreg[8], scv[8]; bool ext[8];
    #pragma unroll
    for (int e = 0; e < 8; ++e) {
        int v = t * 8 + e;
        u64 k = bestE[v];
        kk[e] = k;
        unsigned id = (unsigned)(k & 0x3FFFFFu);
        int a = (int)(id >> 11), b = (int)(id & 2047);
        oreg[e] = (a == v) ? b : a;
        scv[e] = sc[v];
        ext[e] = (k != INVALID_KEY) && (sc[oreg[e]] != scv[e]);
        if (ext[e]) atomicMin(&compW[scv[e]], (unsigned)(k >> 22));
    }
    __syncthreads();
    #pragma unroll
    for (int e = 0; e < 8; ++e)
        if (ext[e] && (unsigned)(kk[e] >> 22) == compW[scv[e]])
            atomicMin(&compI[scv[e]], (unsigned)(kk[e] & 0x3FFFFFu));
    __syncthreads();

    // hook roots; block 0 records edge weights
    bool isr[8];
    #pragma unroll
    for (int e = 0; e < 8; ++e) {
        int c = t * 8 + e;
        int p = c;
        isr[e] = (sc[c] == c);
        if (isr[e]) {
            unsigned wv = compW[c];
            if (wv != 0xFFFFFFFFu) {
                unsigned id = compI[c];
                int a = (int)(id >> 11), b = (int)(id & 2047);
                int j = (sc[a] == c) ? b : a;
                int rj = sc[j];
                bool mutual = (compW[rj] == wv) && (compI[rj] == id);
                if (!(mutual && c < rj)) {
                    p = rj;
                    if (bid == 0) ew[atomicAdd(&s_ecnt, 1)] = __uint_as_float(wv);
                }
            }
        }
        par[c] = p;
    }
    int any = __syncthreads_or(1);
    do {
        int local = 0;
        #pragma unroll
        for (int e = 0; e < 8; ++e) {
            if (isr[e]) {
                int c = t * 8 + e;
                int p = par[c];
                int np = par[p];
                if (np != p) { par[c] = np; local = 1; }
            }
        }
        any = __syncthreads_or(local);
    } while (any);

    int newsc[8];
    #pragma unroll
    for (int e = 0; e < 8; ++e) newsc[e] = par[sc[t * 8 + e]];
    __syncthreads();

    // compact relabel: rank roots ascending (deterministic, all blocks agree)
    int rflag[8], lc = 0;
    #pragma unroll
    for (int e = 0; e < 8; ++e) {
        rflag[e] = (newsc[e] == t * 8 + e) ? 1 : 0;
        lc += rflag[e];
    }
    int scn = lc;
    #pragma unroll
    for (int d = 1; d < 64; d <<= 1) {
        int o = __shfl_up(scn, d);
        if (lane >= d) scn += o;
    }
    if (lane == 63) s_wsum[w] = scn;
    __syncthreads();
    int wbase = 0;
    for (int i = 0; i < w; ++i) wbase += s_wsum[i];
    const int C = s_wsum[0] + s_wsum[1] + s_wsum[2] + s_wsum[3];
    int rank = wbase + scn - lc;
    #pragma unroll
    for (int e = 0; e < 8; ++e)
        if (rflag[e]) compW[t * 8 + e] = (unsigned)(rank++);   // map[root]=rank
    __syncthreads();
    int csc[8];
    #pragma unroll
    for (int e = 0; e < 8; ++e) csc[e] = (int)compW[newsc[e]];
    __syncthreads();
    #pragma unroll
    for (int e = 0; e < 8; ++e) sc[t * 8 + e] = csc[e];        // sc := csc
    __syncthreads();

    if (bid == 0) {
        #pragma unroll
        for (int e = 0; e < 8; ++e) cscg[t * 8 + e] = csc[e];
        if (t == 0) { ctl[0] = s_ecnt; ctl[1] = C; }
    }

    // ---- condense: block handles rows 4*bid .. 4*bid+3 ----
    #pragma unroll
    for (int e = 0; e < 8; ++e) Mrow[t * 8 + e] = INVALID_KEY;
    __syncthreads();
    const int r = t >> 6;                 // wave r handles row 4*bid+r
    const int v = bid * 4 + r;
    const int cv = sc[v];
    const float* row = D2 + (size_t)v * NPTS;
    #pragma unroll
    for (int k = 0; k < 8; ++k) {
        int j0 = k * 256 + lane * 4;
        float4 w4 = *(const float4*)(row + j0);
        int4 c4 = *(const int4*)(sc + j0);
        float wa[4] = {w4.x, w4.y, w4.z, w4.w};
        int ca[4] = {c4.x, c4.y, c4.z, c4.w};
        #pragma unroll
        for (int e = 0; e < 4; ++e) {
            if (ca[e] != cv) {
                u64 key = mk_key(wa[e], v, j0 + e);
                atomicMin(&Mrow[r * CMAX + ca[e]], key);
            }
        }
    }
    __syncthreads();
    // write M + per-comp cand (thread t covers 8 entries, all in row t>>6)
    u64 lmin = INVALID_KEY;
    #pragma unroll
    for (int e = 0; e < 8; ++e) {
        int idx = t * 8 + e;
        u64 mv = Mrow[idx];
        if (mv != INVALID_KEY) {
            atomicMin(&M[(size_t)cv * CMAX + (idx & (CMAX - 1))], mv);
            lmin = (mv < lmin) ? mv : lmin;
        }
    }
    for (int off = 32; off; off >>= 1) {
        u64 o = __shfl_down(lmin, off);
        lmin = (o < lmin) ? o : lmin;
    }
    if (lane == 0 && lmin != INVALID_KEY) atomicMin(&cand[cv], lmin);
}

// ---- Kernel 5: all remaining rounds on condensed graph + sort (1 block) --
__global__ __launch_bounds__(1024) void boruvka_final(const u64* __restrict__ M,
                                                      const u64* __restrict__ cand,
                                                      const int* __restrict__ cscg,
                                                      float* __restrict__ ew,
                                                      float* __restrict__ out,
                                                      const int* __restrict__ ctl) {
    __shared__ int comp[CMAX];
    __shared__ u64 candL[CMAX];
    __shared__ u64 compBest[CMAX];
    __shared__ int oth[CMAX];
    __shared__ int par[CMAX];
    __shared__ int flg[CMAX];
    __shared__ int cscL[NPTS];
    __shared__ float wl[NPTS];
    __shared__ int s_ecnt, s_nroots;
    const int t = threadIdx.x;
    const int lane = t & 63, wv = t >> 6;
    const int C = ctl[1];

    if (t == 0) s_ecnt = ctl[0];
    for (int i = t; i < NPTS; i += 1024) cscL[i] = cscg[i];
    if (t < CMAX) { comp[t] = t; candL[t] = (t < C) ? cand[t] : INVALID_KEY; }
    __syncthreads();
    if (t < C) {
        u64 k = candL[t];
        unsigned id = (unsigned)(k & 0x3FFFFFu);
        int a = (int)(id >> 11), b = (int)(id & 2047);
        int ta = cscL[a];
        oth[t] = (ta == t) ? cscL[b] : ta;
    }
    __syncthreads();

    for (int r = 0; r < 10; ++r) {
        if (t < CMAX) compBest[t] = INVALID_KEY;
        if (t == 0) s_nroots = 0;
        __syncthreads();
        if (t < C) {
            u64 k = candL[t];
            if (comp[oth[t]] != comp[t]) atomicMin(&compBest[comp[t]], k);
        }
        __syncthreads();
        bool isr = false;
        if (t < C) {
            int p = t;
            isr = (comp[t] == t);
            if (isr) {
                u64 k = compBest[t];
                if (k != INVALID_KEY) {
                    unsigned id = (unsigned)(k & 0x3FFFFFu);
                    int a = (int)(id >> 11), b = (int)(id & 2047);
                    int ca = comp[cscL[a]], cb = comp[cscL[b]];
                    int rj = (ca == t) ? cb : ca;
                    bool mutual = (compBest[rj] == k);
                    if (!(mutual && t < rj)) {
                        p = rj;
                        ew[atomicAdd(&s_ecnt, 1)] = __uint_as_float((unsigned)(k >> 22));
                    }
                }
            }
            par[t] = p;
        }
        int any = __syncthreads_or(1);
        do {
            int local = 0;
            if (t < C && isr) {
                int p = par[t];
                int np = par[p];
                if (np != p) { par[t] = np; local = 1; }
            }
            any = __syncthreads_or(local);
        } while (any);
        if (t < C) {
            int nc = par[comp[t]];
            comp[t] = nc;
            if (nc == t) atomicAdd(&s_nroots, 1);
        }
        __syncthreads();
        if (s_nroots == 1) break;
        if (t < C) flg[t] = (comp[oth[t]] == comp[t]) ? 1 : 0;
        __syncthreads();
        // rescan invalidated original-comps: wave per comp, strided
        for (int c = wv; c < C; c += 16) {
            if (flg[c]) {
                const u64* mr = M + (size_t)c * CMAX;
                int mc = comp[c];
                u64 best = INVALID_KEY; int bj = 0;
                #pragma unroll
                for (int s = 0; s < 8; ++s) {
                    int j = s * 64 + lane;
                    u64 mv = mr[j];
                    if (mv != INVALID_KEY && comp[j] != mc) {
                        if (mv < best) { best = mv; bj = j; }
                    }
                }
                for (int off = 32; off; off >>= 1) {
                    u64 o = __shfl_down(best, off);
                    int oj = __shfl_down(bj, off);
                    if (o < best) { best = o; bj = oj; }
                }
                if (lane == 0) { candL[c] = best; oth[c] = bj; }
            }
        }
        __syncthreads();
    }

    // bitonic sort 2048 (2047 edges + inf pad), sqrt, out
    __syncthreads();
    for (int i = t; i < NPTS; i += 1024)
        wl[i] = (i < NPTS - 1) ? ew[i] : __builtin_inff();
    __syncthreads();
    for (int k = 2; k <= NPTS; k <<= 1) {
        for (int j = k >> 1; j > 0; j >>= 1) {
            for (int i = t; i < NPTS; i += 1024) {
                int l = i ^ j;
                if (l > i) {
                    float a = wl[i], b = wl[l];
                    bool up = ((i & k) == 0);
                    if ((a > b) == up) { wl[i] = b; wl[l] = a; }
                }
            }
            __syncthreads();
        }
    }
    for (int i = t; i < NPTS - 1; i += 1024)
        out[i] = sqrtf(fmaxf(wl[i], 0.0f));
}

extern "C" void kernel_launch(void* const* d_in, const int* in_sizes, int n_in,
                              void* d_out, int out_size, void* d_ws, size_t ws_size,
                              hipStream_t stream) {
    const float* x = (const float*)d_in[0];
    float* out = (float*)d_out;
    char* ws = (char*)d_ws;
    unsigned short* xb = (unsigned short*)ws;                 // 16 MB (dead after gemm)
    u64* M    = (u64*)ws;                                     // 2 MB, overlays dead xb
    u64* cand = (u64*)(ws + 2097152);                         // 4 KB
    int* cscg = (int*)(ws + 2097152 + 4096);                  // 8 KB
    float* D2 = (float*)(ws + 16777216);                      // 16 MB
    size_t o = 33554432;
    float* sq = (float*)(ws + o);                  o += 8192;
    u64* best0 = (u64*)(ws + o);                   o += 16384;
    u64* best1 = (u64*)(ws + o);                   o += 16384;
    int* comp = (int*)(ws + o);                    o += 8192;
    float* ew = (float*)(ws + o);                  o += 8192;
    int* ctl = (int*)(ws + o);

    hipLaunchKernelGGL(convert_sqnorm_kernel, dim3(NPTS), dim3(256), 0, stream,
                       x, xb, sq, best0, ctl);
    hipLaunchKernelGGL(gemm_d2_glds, dim3(16, 32), dim3(256), 0, stream,
                       xb, sq, D2, best0);
    hipLaunchKernelGGL(boruvka_round1, dim3(512), dim3(256), 0, stream,
                       D2, best0, best1, comp, ew, ctl, M, cand);
    hipLaunchKernelGGL(boruvka_r2_condense, dim3(512), dim3(256), 0, stream,
                       D2, best1, comp, ew, ctl, cscg, M, cand);
    hipLaunchKernelGGL(boruvka_final, dim3(1), dim3(1024), 0, stream,
                       M, cand, cscg, ew, out, ctl);
}

// Round 11
// 238.022 us; speedup vs baseline: 2.1705x; 1.0288x over previous
//
#include <hip/hip_runtime.h>
#include <stdint.h>

#define NPTS 2048
#define KDIM 4096
#define CMAX 512
#define INVALID_KEY 0xFFFFFFFFFFFFFFFFull

typedef __bf16 bf16x8 __attribute__((ext_vector_type(8)));
typedef float f32x4 __attribute__((ext_vector_type(4)));
typedef unsigned long long u64;

__device__ __forceinline__ unsigned short f2bf(float f) {
    unsigned int u = __float_as_uint(f);
    u = (u + 0x7FFFu + ((u >> 16) & 1u)) >> 16;   // RNE
    return (unsigned short)u;
}

__device__ __forceinline__ void gld_lds16(const unsigned short* g, unsigned short* l) {
    __builtin_amdgcn_global_load_lds(
        (const __attribute__((address_space(1))) unsigned int*)g,
        (__attribute__((address_space(3))) unsigned int*)l, 16, 0, 0);
}

// key = (d2_bits << 22) | (min(i,j) << 11) | max(i,j): unique per undirected
// edge -> tie-free total order; uniqueness survives contraction.
__device__ __forceinline__ u64 mk_key(float w, int i, int j) {
    u64 a = (i < j) ? i : j;
    u64 b = (i < j) ? j : i;
    return ((u64)__float_as_uint(w) << 22) | (a << 11) | b;
}

// ---- Kernel 1: fp32->bf16 convert + sqnorm + state init ------------------
__global__ __launch_bounds__(256) void convert_sqnorm_kernel(const float* __restrict__ x,
                                                             unsigned short* __restrict__ xb,
                                                             float* __restrict__ sq,
                                                             u64* __restrict__ best0,
                                                             int* __restrict__ ctl) {
    const int row = blockIdx.x;
    const float* xr = x + (size_t)row * KDIM;
    unsigned short* xbr = xb + (size_t)row * KDIM;
    const int t = threadIdx.x;
    float s = 0.f;
    #pragma unroll
    for (int k = 0; k < 4; ++k) {
        int c = t * 4 + k * 1024;
        float4 v = *(const float4*)(xr + c);
        s += v.x * v.x + v.y * v.y + v.z * v.z + v.w * v.w;
        uint2 u;
        u.x = (unsigned)f2bf(v.x) | ((unsigned)f2bf(v.y) << 16);
        u.y = (unsigned)f2bf(v.z) | ((unsigned)f2bf(v.w) << 16);
        *(uint2*)(xbr + c) = u;
    }
    for (int off = 32; off; off >>= 1) s += __shfl_down(s, off);
    __shared__ float p[4];
    if ((t & 63) == 0) p[t >> 6] = s;
    __syncthreads();
    if (t == 0) {
        sq[row] = p[0] + p[1] + p[2] + p[3];
        best0[row] = INVALID_KEY;
        if (row == 0) { ctl[0] = 0; ctl[1] = 0; }
    }
}

// ---- Kernel 2: GEMM D2, BK=64, conflict-free swizzled gLDS, fused r0 scan
// 64x128 tile, 24 chunks of 1KB (8 rows x 128B each). Lane l of a chunk
// fetches global granule (l&7)^((l>>3)&7) of row l>>3, so LDS slot s of row
// r holds granule s^(r&7); reader granule ks*4+q lands on bank-quad
// (ks*4+q)^(m&7) -> uniform over the wave -> conflict-free.
__global__ __launch_bounds__(256, 2) void gemm_d2_glds(const unsigned short* __restrict__ xb,
                                                       const float* __restrict__ sq,
                                                       float* __restrict__ D2,
                                                       u64* __restrict__ best0) {
    __shared__ __align__(16) unsigned short tile[24 * 512];  // 24 KB: 0-7 A, 8-23 B
    const int I0 = blockIdx.y * 64;
    const int J0 = blockIdx.x * 128;
    const int t = threadIdx.x;
    const int lane = t & 63;
    const int w = t >> 6;
    const int m = lane & 15, q = lane >> 4;
    const int mq7 = m & 7, mh = m >> 3;

    const int rp = lane >> 3;                 // row within chunk (0..7)
    const int sg = (lane & 7) ^ rp;           // granule to fetch (swizzle)
    const unsigned short* gsrc[6]; unsigned short* ldst[6];
    #pragma unroll
    for (int ci = 0; ci < 6; ++ci) {
        int c = w * 6 + ci;
        int rowbase = (c < 8) ? (I0 + c * 8) : (J0 + (c - 8) * 8);
        gsrc[ci] = xb + (size_t)(rowbase + rp) * KDIM + sg * 8;
        ldst[ci] = tile + c * 512;            // wave-uniform base; HW adds lane*16B
    }

    f32x4 acc[4][2] = {};
    for (int kc = 0; kc < KDIM; kc += 64) {
        #pragma unroll
        for (int ci = 0; ci < 6; ++ci) gld_lds16(gsrc[ci] + kc, ldst[ci]);
        __syncthreads();
        #pragma unroll
        for (int ks = 0; ks < 2; ++ks) {
            const int go = ((ks * 4 + q) ^ mq7) * 8;   // swizzled granule offset
            bf16x8 af[4], bg[2];
            #pragma unroll
            for (int rt = 0; rt < 4; ++rt)
                af[rt] = *(const bf16x8*)(tile + (rt * 2 + mh) * 512 + mq7 * 64 + go);
            #pragma unroll
            for (int ct = 0; ct < 2; ++ct)
                bg[ct] = *(const bf16x8*)(tile + 4096 + (w * 4 + ct * 2 + mh) * 512 + mq7 * 64 + go);
            #pragma unroll
            for (int rt = 0; rt < 4; ++rt)
                #pragma unroll
                for (int ct = 0; ct < 2; ++ct)
                    acc[rt][ct] = __builtin_amdgcn_mfma_f32_16x16x32_bf16(
                        af[rt], bg[ct], acc[rt][ct], 0, 0, 0);
        }
        __syncthreads();
    }

    // Epilogue: store D2 + fused per-row min-key (round-0 scan).
    // C/D: col = lane&15, row = q*4+reg  [m89/m91-verified]
    u64* s_best = (u64*)tile;
    if (t < 64) s_best[t] = INVALID_KEY;
    __syncthreads();
    #pragma unroll
    for (int rt = 0; rt < 4; ++rt) {
        #pragma unroll
        for (int r = 0; r < 4; ++r) {
            int i = I0 + rt * 16 + q * 4 + r;
            u64 kk = INVALID_KEY;
            #pragma unroll
            for (int ct = 0; ct < 2; ++ct) {
                int j = J0 + w * 32 + ct * 16 + m;
                float v = sq[i] + sq[j] - 2.0f * acc[rt][ct][r];
                v = (i == j) ? __builtin_inff() : fmaxf(v, 0.0f);
                D2[(size_t)i * NPTS + j] = v;
                if (i != j) {
                    u64 key = mk_key(v, i, j);
                    kk = (key < kk) ? key : kk;
                }
            }
            #pragma unroll
            for (int mask = 1; mask < 16; mask <<= 1) {
                u64 o = __shfl_xor(kk, mask);
                kk = (o < kk) ? o : kk;
            }
            if (m == 0) atomicMin(&s_best[rt * 16 + q * 4 + r], kk);
        }
    }
    __syncthreads();
    if (t < 64) atomicMin(&best0[I0 + t], s_best[t]);
}

// ---- Kernel 3: round 1 (identity comps, atomic-free merge) + M/cand init -
__global__ __launch_bounds__(256) void boruvka_round1(const float* __restrict__ D2,
                                                      const u64* __restrict__ bestP,
                                                      u64* __restrict__ bestN,
                                                      int* __restrict__ compN,
                                                      float* __restrict__ ew,
                                                      int* __restrict__ ctl,
                                                      u64* __restrict__ M,
                                                      u64* __restrict__ cand) {
    __shared__ unsigned compW[NPTS];
    __shared__ unsigned compI[NPTS];
    __shared__ int sc[NPTS];
    __shared__ int par[NPTS];
    __shared__ int s_wsum[4];
    __shared__ int s_ecnt;
    const int t = threadIdx.x;
    const int bid = blockIdx.x;
    const int lane = t & 63, w = t >> 6;

    {
        u64* Mb = M + (size_t)bid * CMAX;
        Mb[t] = INVALID_KEY; Mb[t + 256] = INVALID_KEY;
        if (t == 0) cand[bid] = INVALID_KEY;
    }

    if (t == 0) s_ecnt = 0;
    int oreg[8];
    #pragma unroll
    for (int e = 0; e < 8; ++e) {
        int v = t * 8 + e;
        u64 k = bestP[v];
        unsigned id = (unsigned)(k & 0x3FFFFFu);
        compW[v] = (unsigned)(k >> 22);
        compI[v] = id;
        int a = (int)(id >> 11), b = (int)(id & 2047);
        oreg[e] = (a == v) ? b : a;
    }
    __syncthreads();

    #pragma unroll
    for (int e = 0; e < 8; ++e) {
        int c = t * 8 + e;
        unsigned id = compI[c];
        int j = oreg[e];
        bool mutual = (compI[j] == id);
        int p;
        if (mutual && c < j) p = c;
        else {
            p = j;
            if (bid == 0) ew[atomicAdd(&s_ecnt, 1)] = __uint_as_float(compW[c]);
        }
        par[c] = p;
    }
    int any = __syncthreads_or(1);
    do {
        int local = 0;
        #pragma unroll
        for (int e = 0; e < 8; ++e) {
            int c = t * 8 + e;
            int p = par[c];
            int np = par[p];
            if (np != p) { par[c] = np; local = 1; }
        }
        any = __syncthreads_or(local);
    } while (any);

    int newsc[8];
    #pragma unroll
    for (int e = 0; e < 8; ++e) newsc[e] = par[t * 8 + e];
    __syncthreads();
    #pragma unroll
    for (int e = 0; e < 8; ++e) sc[t * 8 + e] = newsc[e];
    __syncthreads();

    if (bid == 0) {
        #pragma unroll
        for (int e = 0; e < 8; ++e) compN[t * 8 + e] = newsc[e];
        if (t == 0) ctl[0] = s_ecnt;
    }

    int flags[8], lc = 0;
    #pragma unroll
    for (int e = 0; e < 8; ++e) {
        flags[e] = (sc[oreg[e]] == newsc[e]) ? 1 : 0;
        lc += flags[e];
    }
    int scn = lc;
    #pragma unroll
    for (int d = 1; d < 64; d <<= 1) {
        int o = __shfl_up(scn, d);
        if (lane >= d) scn += o;
    }
    if (lane == 63) s_wsum[w] = scn;
    __syncthreads();
    int wbase = 0;
    for (int i = 0; i < w; ++i) wbase += s_wsum[i];
    const int ncand = s_wsum[0] + s_wsum[1] + s_wsum[2] + s_wsum[3];
    int base = wbase + scn - lc;
    int* rlist = par;
    #pragma unroll
    for (int e = 0; e < 8; ++e)
        if (flags[e]) rlist[base++] = t * 8 + e;
    __syncthreads();

    if (t < 4) {
        int v = bid * 4 + t;
        u64 k = bestP[v];
        unsigned id = (unsigned)(k & 0x3FFFFFu);
        int a = (int)(id >> 11), b = (int)(id & 2047);
        int o = (a == v) ? b : a;
        if (sc[o] != sc[v]) bestN[v] = k;
    }
    int widx = bid * 4 + w;
    if (widx < ncand) {
        int v = rlist[widx];
        int mc = sc[v];
        const float* row = D2 + (size_t)v * NPTS;
        u64 best = INVALID_KEY;
        #pragma unroll
        for (int k = 0; k < 8; ++k) {
            int j0 = k * 256 + lane * 4;
            float4 w4 = *(const float4*)(row + j0);
            int4 c4 = *(const int4*)(sc + j0);
            float wa[4] = {w4.x, w4.y, w4.z, w4.w};
            int ca[4] = {c4.x, c4.y, c4.z, c4.w};
            #pragma unroll
            for (int e = 0; e < 4; ++e) {
                if (ca[e] != mc) {
                    u64 key = mk_key(wa[e], v, j0 + e);
                    best = (key < best) ? key : best;
                }
            }
        }
        for (int off = 32; off; off >>= 1) {
            u64 o = __shfl_down(best, off);
            best = (o < best) ? o : best;
        }
        if (lane == 0) bestN[v] = best;
    }
}

// ---- Kernel 4: round-2 merge + compact relabel + condense to M[512][512] -
__global__ __launch_bounds__(256) void boruvka_r2_condense(const float* __restrict__ D2,
                                                           const u64* __restrict__ bestE,
                                                           const int* __restrict__ compIn,
                                                           float* __restrict__ ew,
                                                           int* __restrict__ ctl,
                                                           int* __restrict__ cscg,
                                                           u64* __restrict__ M,
                                                           u64* __restrict__ cand) {
    __shared__ __align__(16) char smem[32768];
    int* sc         = (int*)smem;               // 8 KB (comp, later csc)
    unsigned* compW = (unsigned*)(smem + 8192);
    unsigned* compI = (unsigned*)(smem + 16384);
    int* par        = (int*)(smem + 24576);
    u64* Mrow       = (u64*)(smem + 8192);      // 16 KB overlay (4 x 512 u64)
    __shared__ int s_wsum[4];
    __shared__ int s_ecnt;
    const int t = threadIdx.x;
    const int bid = blockIdx.x;
    const int lane = t & 63, w = t >> 6;

    if (t == 0) s_ecnt = ctl[0];
    #pragma unroll
    for (int e = 0; e < 8; ++e) {
        int v = t * 8 + e;
        sc[v] = compIn[v];
        compW[v] = 0xFFFFFFFFu;
        compI[v] = 0xFFFFFFFFu;
    }
    __syncthreads();

    u64 kk[8]; int oreg[8], scv[8]; bool ext[8];
    #pragma unroll
    for (int e = 0; e < 8; ++e) {
        int v = t * 8 + e;
        u64 k = bestE[v];
        kk[e] = k;
        unsigned id = (unsigned)(k & 0x3FFFFFu);
        int a = (int)(id >> 11), b = (int)(id & 2047);
        oreg[e] = (a == v) ? b : a;
        scv[e] = sc[v];
        ext[e] = (k != INVALID_KEY) && (sc[oreg[e]] != scv[e]);
        if (ext[e]) atomicMin(&compW[scv[e]], (unsigned)(k >> 22));
    }
    __syncthreads();
    #pragma unroll
    for (int e = 0; e < 8; ++e)
        if (ext[e] && (unsigned)(kk[e] >> 22) == compW[scv[e]])
            atomicMin(&compI[scv[e]], (unsigned)(kk[e] & 0x3FFFFFu));
    __syncthreads();

    bool isr[8];
    #pragma unroll
    for (int e = 0; e < 8; ++e) {
        int c = t * 8 + e;
        int p = c;
        isr[e] = (sc[c] == c);
        if (isr[e]) {
            unsigned wv = compW[c];
            if (wv != 0xFFFFFFFFu) {
                unsigned id = compI[c];
                int a = (int)(id >> 11), b = (int)(id & 2047);
                int j = (sc[a] == c) ? b : a;
                int rj = sc[j];
                bool mutual = (compW[rj] == wv) && (compI[rj] == id);
                if (!(mutual && c < rj)) {
                    p = rj;
                    if (bid == 0) ew[atomicAdd(&s_ecnt, 1)] = __uint_as_float(wv);
                }
            }
        }
        par[c] = p;
    }
    int any = __syncthreads_or(1);
    do {
        int local = 0;
        #pragma unroll
        for (int e = 0; e < 8; ++e) {
            if (isr[e]) {
                int c = t * 8 + e;
                int p = par[c];
                int np = par[p];
                if (np != p) { par[c] = np; local = 1; }
            }
        }
        any = __syncthreads_or(local);
    } while (any);

    int newsc[8];
    #pragma unroll
    for (int e = 0; e < 8; ++e) newsc[e] = par[sc[t * 8 + e]];
    __syncthreads();

    // compact relabel: rank roots ascending (deterministic, all blocks agree)
    int rflag[8], lc = 0;
    #pragma unroll
    for (int e = 0; e < 8; ++e) {
        rflag[e] = (newsc[e] == t * 8 + e) ? 1 : 0;
        lc += rflag[e];
    }
    int scn = lc;
    #pragma unroll
    for (int d = 1; d < 64; d <<= 1) {
        int o = __shfl_up(scn, d);
        if (lane >= d) scn += o;
    }
    if (lane == 63) s_wsum[w] = scn;
    __syncthreads();
    int wbase = 0;
    for (int i = 0; i < w; ++i) wbase += s_wsum[i];
    const int C = s_wsum[0] + s_wsum[1] + s_wsum[2] + s_wsum[3];
    int rank = wbase + scn - lc;
    #pragma unroll
    for (int e = 0; e < 8; ++e)
        if (rflag[e]) compW[t * 8 + e] = (unsigned)(rank++);   // map[root]=rank
    __syncthreads();
    int csc[8];
    #pragma unroll
    for (int e = 0; e < 8; ++e) csc[e] = (int)compW[newsc[e]];
    __syncthreads();
    #pragma unroll
    for (int e = 0; e < 8; ++e) sc[t * 8 + e] = csc[e];
    __syncthreads();

    if (bid == 0) {
        #pragma unroll
        for (int e = 0; e < 8; ++e) cscg[t * 8 + e] = csc[e];
        if (t == 0) { ctl[0] = s_ecnt; ctl[1] = C; }
    }

    // ---- condense: block handles rows 4*bid .. 4*bid+3 ----
    #pragma unroll
    for (int e = 0; e < 8; ++e) Mrow[t * 8 + e] = INVALID_KEY;
    __syncthreads();
    const int r = t >> 6;
    const int v = bid * 4 + r;
    const int cv = sc[v];
    const float* row = D2 + (size_t)v * NPTS;
    #pragma unroll
    for (int k = 0; k < 8; ++k) {
        int j0 = k * 256 + lane * 4;
        float4 w4 = *(const float4*)(row + j0);
        int4 c4 = *(const int4*)(sc + j0);
        float wa[4] = {w4.x, w4.y, w4.z, w4.w};
        int ca[4] = {c4.x, c4.y, c4.z, c4.w};
        #pragma unroll
        for (int e = 0; e < 4; ++e) {
            if (ca[e] != cv) {
                u64 key = mk_key(wa[e], v, j0 + e);
                // monotone-high filter: high word only decreases; tear-free
                unsigned ch = ((volatile unsigned*)&Mrow[r * CMAX + ca[e]])[1];
                if ((unsigned)(key >> 32) <= ch)
                    atomicMin(&Mrow[r * CMAX + ca[e]], key);
            }
        }
    }
    __syncthreads();
    u64 lmin = INVALID_KEY;
    #pragma unroll
    for (int e = 0; e < 8; ++e) {
        int idx = t * 8 + e;
        u64 mv = Mrow[idx];
        if (mv != INVALID_KEY) {
            u64* mp = &M[(size_t)cv * CMAX + (idx & (CMAX - 1))];
            unsigned ch = ((volatile unsigned*)mp)[1];
            if ((unsigned)(mv >> 32) <= ch) atomicMin(mp, mv);
            lmin = (mv < lmin) ? mv : lmin;
        }
    }
    for (int off = 32; off; off >>= 1) {
        u64 o = __shfl_down(lmin, off);
        lmin = (o < lmin) ? o : lmin;
    }
    if (lane == 0 && lmin != INVALID_KEY) atomicMin(&cand[cv], lmin);
}

// ---- Kernel 5: all remaining rounds on condensed graph + sort (1 block) --
__global__ __launch_bounds__(1024) void boruvka_final(const u64* __restrict__ M,
                                                      const u64* __restrict__ cand,
                                                      const int* __restrict__ cscg,
                                                      float* __restrict__ ew,
                                                      float* __restrict__ out,
                                                      const int* __restrict__ ctl) {
    __shared__ int comp[CMAX];
    __shared__ u64 candL[CMAX];
    __shared__ u64 compBest[CMAX];
    __shared__ int oth[CMAX];
    __shared__ int par[CMAX];
    __shared__ int flg[CMAX];
    __shared__ int cscL[NPTS];
    __shared__ float wl[NPTS];
    __shared__ int s_ecnt, s_nroots;
    const int t = threadIdx.x;
    const int lane = t & 63, wv = t >> 6;
    const int C = ctl[1];

    if (t == 0) s_ecnt = ctl[0];
    for (int i = t; i < NPTS; i += 1024) cscL[i] = cscg[i];
    if (t < CMAX) { comp[t] = t; candL[t] = (t < C) ? cand[t] : INVALID_KEY; }
    __syncthreads();
    if (t < C) {
        u64 k = candL[t];
        unsigned id = (unsigned)(k & 0x3FFFFFu);
        int a = (int)(id >> 11), b = (int)(id & 2047);
        int ta = cscL[a];
        oth[t] = (ta == t) ? cscL[b] : ta;
    }
    __syncthreads();

    for (int r = 0; r < 10; ++r) {
        if (t < CMAX) compBest[t] = INVALID_KEY;
        if (t == 0) s_nroots = 0;
        __syncthreads();
        if (t < C) {
            u64 k = candL[t];
            if (comp[oth[t]] != comp[t]) atomicMin(&compBest[comp[t]], k);
        }
        __syncthreads();
        bool isr = false;
        if (t < C) {
            int p = t;
            isr = (comp[t] == t);
            if (isr) {
                u64 k = compBest[t];
                if (k != INVALID_KEY) {
                    unsigned id = (unsigned)(k & 0x3FFFFFu);
                    int a = (int)(id >> 11), b = (int)(id & 2047);
                    int ca = comp[cscL[a]], cb = comp[cscL[b]];
                    int rj = (ca == t) ? cb : ca;
                    bool mutual = (compBest[rj] == k);
                    if (!(mutual && t < rj)) {
                        p = rj;
                        ew[atomicAdd(&s_ecnt, 1)] = __uint_as_float((unsigned)(k >> 22));
                    }
                }
            }
            par[t] = p;
        }
        int any = __syncthreads_or(1);
        do {
            int local = 0;
            if (t < C && isr) {
                int p = par[t];
                int np = par[p];
                if (np != p) { par[t] = np; local = 1; }
            }
            any = __syncthreads_or(local);
        } while (any);
        if (t < C) {
            int nc = par[comp[t]];
            comp[t] = nc;
            if (nc == t) atomicAdd(&s_nroots, 1);
        }
        __syncthreads();
        if (s_nroots == 1) break;
        if (t < C) flg[t] = (comp[oth[t]] == comp[t]) ? 1 : 0;
        __syncthreads();
        for (int c = wv; c < C; c += 16) {
            if (flg[c]) {
                const u64* mr = M + (size_t)c * CMAX;
                int mc = comp[c];
                u64 best = INVALID_KEY; int bj = 0;
                #pragma unroll
                for (int s = 0; s < 8; ++s) {
                    int j = s * 64 + lane;
                    u64 mv = mr[j];
                    if (mv != INVALID_KEY && comp[j] != mc) {
                        if (mv < best) { best = mv; bj = j; }
                    }
                }
                for (int off = 32; off; off >>= 1) {
                    u64 o = __shfl_down(best, off);
                    int oj = __shfl_down(bj, off);
                    if (o < best) { best = o; bj = oj; }
                }
                if (lane == 0) { candL[c] = best; oth[c] = bj; }
            }
        }
        __syncthreads();
    }

    __syncthreads();
    for (int i = t; i < NPTS; i += 1024)
        wl[i] = (i < NPTS - 1) ? ew[i] : __builtin_inff();
    __syncthreads();
    for (int k = 2; k <= NPTS; k <<= 1) {
        for (int j = k >> 1; j > 0; j >>= 1) {
            for (int i = t; i < NPTS; i += 1024) {
                int l = i ^ j;
                if (l > i) {
                    float a = wl[i], b = wl[l];
                    bool up = ((i & k) == 0);
                    if ((a > b) == up) { wl[i] = b; wl[l] = a; }
                }
            }
            __syncthreads();
        }
    }
    for (int i = t; i < NPTS - 1; i += 1024)
        out[i] = sqrtf(fmaxf(wl[i], 0.0f));
}

extern "C" void kernel_launch(void* const* d_in, const int* in_sizes, int n_in,
                              void* d_out, int out_size, void* d_ws, size_t ws_size,
                              hipStream_t stream) {
    const float* x = (const float*)d_in[0];
    float* out = (float*)d_out;
    char* ws = (char*)d_ws;
    unsigned short* xb = (unsigned short*)ws;                 // 16 MB (dead after gemm)
    u64* M    = (u64*)ws;                                     // 2 MB, overlays dead xb
    u64* cand = (u64*)(ws + 2097152);                         // 4 KB
    int* cscg = (int*)(ws + 2097152 + 4096);                  // 8 KB
    float* D2 = (float*)(ws + 16777216);                      // 16 MB
    size_t o = 33554432;
    float* sq = (float*)(ws + o);                  o += 8192;
    u64* best0 = (u64*)(ws + o);                   o += 16384;
    u64* best1 = (u64*)(ws + o);                   o += 16384;
    int* comp = (int*)(ws + o);                    o += 8192;
    float* ew = (float*)(ws + o);                  o += 8192;
    int* ctl = (int*)(ws + o);

    hipLaunchKernelGGL(convert_sqnorm_kernel, dim3(NPTS), dim3(256), 0, stream,
                       x, xb, sq, best0, ctl);
    hipLaunchKernelGGL(gemm_d2_glds, dim3(16, 32), dim3(256), 0, stream,
                       xb, sq, D2, best0);
    hipLaunchKernelGGL(boruvka_round1, dim3(512), dim3(256), 0, stream,
                       D2, best0, best1, comp, ew, ctl, M, cand);
    hipLaunchKernelGGL(boruvka_r2_condense, dim3(512), dim3(256), 0, stream,
                       D2, best1, comp, ew, ctl, cscg, M, cand);
    hipLaunchKernelGGL(boruvka_final, dim3(1), dim3(1024), 0, stream,
                       M, cand, cscg, ew, out, ctl);
}